// Round 16
// baseline (31.833 us; speedup 1.0000x reference)
//
#include <hip/hip_runtime.h>
#include <stdint.h>

#define HW 128
#define PLANE (HW * HW)              // 16384
#define SCALE 0.17677669529663687f   // 32^-0.5
#define FENCE() asm volatile("" ::: "memory")
#define VMW(N) asm volatile("s_waitcnt vmcnt(" #N ")" ::: "memory")
#define BAR() __builtin_amdgcn_s_barrier()

// async global->LDS: per-lane global src, wave-uniform LDS dst + lane*16
__device__ __forceinline__ void dma16(const float* g, float* l) {
  __builtin_amdgcn_global_load_lds(
      (const __attribute__((address_space(1))) void*)g,
      (__attribute__((address_space(3))) void*)l, 16, 0, 0);
}

// R15 compute/store structure + LDS-staged k/v (3x -> 1x global reads).
// Block = one (b,head) x 8-row tile x 128px, 512 thr (8 waves); thread =
// 4px x 16ch, lane=(strip<<1)|h2; XCD swizzle as R15. k/v staged per
// 8-channel group as [8ch][10rows][128px] 40KB LDS tiles, 3 buffers (120KB),
// 2-deep prefetch via global_load_lds (wave w stages channel w: 5 dma16 of
// 1KB each), counted-vmcnt ladder (position-audited; never 0 mid-loop),
// 8 groups x {dma, vmcnt, bar, compute, bar}. q loaded direct (1x traffic).
// Global wave-instrs 128 -> 72; logical k/v reads 201 -> 84 MB.
__global__ __launch_bounds__(512, 2) void natt3x3_kernel(
    const float* __restrict__ q,
    const float* __restrict__ k,
    const float* __restrict__ v,
    float* __restrict__ out) {
  __shared__ __align__(16) float smem[3 * 10240];   // 3 bufs x 8ch x 10rows x 128px

  const int tid  = threadIdx.x;
  const int lane = tid & 63;
  const int w    = tid >> 6;            // wave = output row in tile (0..7)
  const int h2   = lane & 1;
  const int s    = lane >> 1;           // strip 0..31
  const int x0   = s << 2;
  const int bid  = blockIdx.x;
  const int img   = ((bid & 7) << 1) | ((bid >> 3) & 1);   // XCD swizzle (R15)
  const int ytile = bid >> 4;                              // 0..15
  const int head  = img & 3;
  const int b     = img >> 2;
  const int y0    = ytile << 3;
  const int y     = y0 + w;

  const size_t ibase = (size_t)(b * 128 + head * 32) * PLANE;      // staging base
  const size_t cbase = ibase + (size_t)(h2 * 4) * PLANE;           // q/out base
  const int yx = y * HW + x0;

  // staging lane parts: wave w stages channel (g*8+w), rows y0-1..y0+8.
  // instr j stages LDS rows 2j (lanes 0-31) and 2j+1 (lanes 32-63).
  const int hi  = lane >> 5;
  const int spx = (lane & 31) << 2;
  int srow[5];
#pragma unroll
  for (int j = 0; j < 5; ++j) {
    int rg = y0 - 1 + 2 * j + hi;
    rg = rg < 0 ? 0 : (rg > HW - 1 ? HW - 1 : rg);   // clamp; mask fixes value
    srow[j] = rg * HW + spx;
  }
  float* const dwave = smem + w * 1280;   // my 5KB slab; + buf*10240 + j*256

  float l[4][9];
#pragma unroll
  for (int i = 0; i < 4; ++i)
#pragma unroll
    for (int j = 0; j < 9; ++j) l[i][j] = 0.f;
  float acc[4][16];
#pragma unroll
  for (int i = 0; i < 4; ++i)
#pragma unroll
    for (int c = 0; c < 16; ++c) acc[i][c] = 0.f;
  float4 qA[4], qB[4];

#define DMA(BUF, PTR, G) do {                                                 \
    const float* sb = (PTR) + ibase + (size_t)((G) * 8 + w) * PLANE;          \
    float* db = dwave + (BUF) * 10240;                                        \
    _Pragma("unroll")                                                         \
    for (int j = 0; j < 5; ++j) dma16(sb + srow[j], db + j * 256);            \
  } while (0)

#define LQ(QW, G) do {                                                        \
    const float* qg = q + cbase + (size_t)((G) * 8) * PLANE + yx;             \
    _Pragma("unroll")                                                         \
    for (int c = 0; c < 4; ++c)                                               \
      QW[c] = *reinterpret_cast<const float4*>(qg + (size_t)c * PLANE);       \
  } while (0)

  // LDS tile read: [buf][ch][row][px], ch = h2*4+c, row = w+dy (global y+dy-1)
#define SKV(BUF, C, DY)                                                       \
  (*reinterpret_cast<const float4*>(                                          \
      smem + (BUF) * 10240 + (h2 * 4 + (C)) * 1280 + (w + (DY)) * 128 + x0))

#define CQK(BUF, QW) do {                                                     \
    _Pragma("unroll")                                                         \
    for (int c = 0; c < 4; ++c) {                                             \
      const float qa[4] = {QW[c].x * SCALE, QW[c].y * SCALE,                  \
                           QW[c].z * SCALE, QW[c].w * SCALE};                 \
      _Pragma("unroll")                                                       \
      for (int dy = 0; dy < 3; ++dy) {                                        \
        float4 kq = SKV(BUF, c, dy);                                          \
        float n0 = __shfl_up(kq.w, 2);                                        \
        float n5 = __shfl_down(kq.x, 2);                                      \
        const float n[6] = {n0, kq.x, kq.y, kq.z, kq.w, n5};                  \
        _Pragma("unroll")                                                     \
        for (int i = 0; i < 4; ++i)                                           \
          _Pragma("unroll")                                                   \
          for (int j = 0; j < 3; ++j)                                         \
            l[i][dy * 3 + j] += qa[i] * n[i + j];                             \
      }                                                                       \
    }                                                                         \
  } while (0)

#define CPV(BUF, G) do {                                                      \
    _Pragma("unroll")                                                         \
    for (int c = 0; c < 4; ++c)                                               \
      _Pragma("unroll")                                                       \
      for (int dy = 0; dy < 3; ++dy) {                                        \
        float4 vq = SKV(BUF, c, dy);                                          \
        float n0 = __shfl_up(vq.w, 2);                                        \
        float n5 = __shfl_down(vq.x, 2);                                      \
        const float n[6] = {n0, vq.x, vq.y, vq.z, vq.w, n5};                  \
        _Pragma("unroll")                                                     \
        for (int i = 0; i < 4; ++i)                                           \
          _Pragma("unroll")                                                   \
          for (int j = 0; j < 3; ++j)                                         \
            acc[i][(G) * 4 + c] += l[i][dy * 3 + j] * n[i + j];               \
      }                                                                       \
  } while (0)

  // ---- prologue: q(g0) | dma K0->buf0 | dma K1->buf1 ----
  LQ(qA, 0);     FENCE();
  DMA(0, k, 0);  FENCE();
  DMA(1, k, 1);  FENCE();
  // ---- iter0: stage K2; ladder pos-audited: vmcnt = issued - s_i_end ----
  LQ(qB, 1);     FENCE();
  DMA(2, k, 2);  FENCE();
  VMW(14); BAR(); FENCE();
  CQK(0, qA);    FENCE(); BAR(); FENCE();
  // ---- iter1: stage K3 ----
  LQ(qA, 2);     FENCE();
  DMA(0, k, 3);  FENCE();
  VMW(18); BAR(); FENCE();
  CQK(1, qB);    FENCE(); BAR(); FENCE();
  // ---- iter2: stage V0 ----
  LQ(qB, 3);     FENCE();
  DMA(1, v, 0);  FENCE();
  VMW(18); BAR(); FENCE();
  CQK(2, qA);    FENCE(); BAR(); FENCE();
  // ---- iter3: stage V1; then logit reduce + softmax ----
  DMA(2, v, 1);  FENCE();
  VMW(14); BAR(); FENCE();
  CQK(0, qB);    FENCE();

#pragma unroll
  for (int i = 0; i < 4; ++i)
#pragma unroll
    for (int j = 0; j < 9; ++j) l[i][j] += __shfl_xor(l[i][j], 1);
#pragma unroll
  for (int i = 0; i < 4; ++i) {
    const int xp = x0 + i;
    float mk[9];
#pragma unroll
    for (int dy = 0; dy < 3; ++dy)
#pragma unroll
      for (int dx = 0; dx < 3; ++dx) {
        bool ok = ((unsigned)(y + dy - 1) < (unsigned)HW) &&
                  ((unsigned)(xp + dx - 1) < (unsigned)HW);
        mk[dy * 3 + dx] = ok ? 1.f : 0.f;
      }
    float m = -1e30f;
#pragma unroll
    for (int j = 0; j < 9; ++j) {
      float t = l[i][j] * mk[j];
      l[i][j] = t;
      m = fmaxf(m, t);
    }
    float sum = 0.f;
#pragma unroll
    for (int j = 0; j < 9; ++j) {
      float e = __expf(l[i][j] - m);
      l[i][j] = e;
      sum += e;
    }
    float inv = 1.f / sum;
#pragma unroll
    for (int j = 0; j < 9; ++j) l[i][j] *= inv * mk[j];
  }
  FENCE(); BAR(); FENCE();
  // ---- iter4: stage V2 ----
  DMA(0, v, 2);  FENCE();
  VMW(10); BAR(); FENCE();
  CPV(1, 0);     FENCE(); BAR(); FENCE();
  // ---- iter5: stage V3 ----
  DMA(1, v, 3);  FENCE();
  VMW(10); BAR(); FENCE();
  CPV(2, 1);     FENCE(); BAR(); FENCE();
  // ---- iter6 ----
  VMW(5); BAR(); FENCE();
  CPV(0, 2);     FENCE(); BAR(); FENCE();
  // ---- iter7 ----
  VMW(0); BAR(); FENCE();
  CPV(1, 3);

  // ---- fused store phase: 16 float4 back-to-back (64B-sector-complete) ----
  const size_t obase = ((size_t)(b * PLANE + y * HW)) * 128 + head * 32 + h2 * 4;
#pragma unroll
  for (int i = 0; i < 4; ++i) {
    float* op = out + obase + (size_t)(x0 + i) * 128;
#pragma unroll
    for (int g = 0; g < 4; ++g) {
      float4 o;
      o.x = fmaxf(acc[i][g * 4 + 0], 0.f);
      o.y = fmaxf(acc[i][g * 4 + 1], 0.f);
      o.z = fmaxf(acc[i][g * 4 + 2], 0.f);
      o.w = fmaxf(acc[i][g * 4 + 3], 0.f);
      *reinterpret_cast<float4*>(op + g * 8) = o;
    }
  }

#undef DMA
#undef LQ
#undef SKV
#undef CQK
#undef CPV
}

extern "C" void kernel_launch(void* const* d_in, const int* in_sizes, int n_in,
                              void* d_out, int out_size, void* d_ws, size_t ws_size,
                              hipStream_t stream) {
  const float* q = (const float*)d_in[0];
  const float* k = (const float*)d_in[1];
  const float* v = (const float*)d_in[2];
  float* out = (float*)d_out;
  // grid: 256 blocks (XCD-swizzled decode in-kernel), 512 threads (8 waves)
  natt3x3_kernel<<<256, 512, 0, stream>>>(q, k, v, out);
}

// Round 17
// 30.846 us; speedup vs baseline: 1.0320x; 1.0320x over previous
//
#include <hip/hip_runtime.h>
#include <stdint.h>

#define HW 128
#define PLANE (HW * HW)              // 16384
#define SCALE 0.17677669529663687f   // 32^-0.5
#define FENCE() asm volatile("" ::: "memory")
#define VMW(N) asm volatile("s_waitcnt vmcnt(" #N ")" ::: "memory")
#define BAR() __builtin_amdgcn_s_barrier()

// async global->LDS: per-lane global src, wave-uniform LDS dst + lane*16
__device__ __forceinline__ void dma16(const float* g, float* l) {
  __builtin_amdgcn_global_load_lds(
      (const __attribute__((address_space(1))) void*)g,
      (__attribute__((address_space(3))) void*)l, 16, 0, 0);
}

// R15 compute/store structure + 4-phase / 5-barrier LDS staging (R16's fetch
// cut kept; its 17-barrier lockstep removed). Two 80KB LDS buffers, each a
// 16ch x 10row x 128px half-tile. P1: DMA K-hi->B || QK-lo(A). P2: DMA
// V-lo->A || QK-hi(B)+softmax. P3: DMA V-hi->B || PV-lo(A)+stores. P4:
// PV-hi(B)+stores. Counted vmcnt, position-audited (q-loads older than DMA
// where waited; stores younger). Global instrs/wave 128 -> 72. All R15 wins
// kept: XCD swizzle, 8-row tile, float4, shuffle halo, pair-reduce, fused
// 64B-sector stores. Grid = 256 blocks x 512 thr (8 waves), 1 block/CU.
__global__ __launch_bounds__(512, 1) void natt3x3_kernel(
    const float* __restrict__ q,
    const float* __restrict__ k,
    const float* __restrict__ v,
    float* __restrict__ out) {
  __shared__ __align__(16) float smem[2 * 20480];   // 2 bufs x 16ch x 10rows x 128px

  const int tid  = threadIdx.x;
  const int lane = tid & 63;
  const int w    = tid >> 6;            // wave = output row in tile (0..7)
  const int h2   = lane & 1;
  const int s    = lane >> 1;           // strip 0..31
  const int x0   = s << 2;
  const int bid  = blockIdx.x;
  const int img   = ((bid & 7) << 1) | ((bid >> 3) & 1);   // XCD swizzle
  const int ytile = bid >> 4;                              // 0..15
  const int head  = img & 3;
  const int b     = img >> 2;
  const int y0    = ytile << 3;
  const int y     = y0 + w;

  const size_t ibase = (size_t)(b * 128 + head * 32) * PLANE;
  const size_t cbase = ibase + (size_t)(h2 * 4) * PLANE;
  const int yx = y * HW + x0;

  // staging: wave w stages local channels {2w, 2w+1}, rows y0-1..y0+8.
  // dma instr j covers LDS rows 2j (lanes 0-31), 2j+1 (lanes 32-63).
  const int hi  = lane >> 5;
  const int spx = (lane & 31) << 2;
  int srow[5];
#pragma unroll
  for (int j = 0; j < 5; ++j) {
    int rg = y0 - 1 + 2 * j + hi;
    rg = rg < 0 ? 0 : (rg > HW - 1 ? HW - 1 : rg);   // clamp; mask fixes value
    srow[j] = rg * HW + spx;
  }

  float l[4][9];
#pragma unroll
  for (int i = 0; i < 4; ++i)
#pragma unroll
    for (int j = 0; j < 9; ++j) l[i][j] = 0.f;
  float acc[4][16];
#pragma unroll
  for (int i = 0; i < 4; ++i)
#pragma unroll
    for (int c = 0; c < 16; ++c) acc[i][c] = 0.f;
  float4 qv0[4], qv1[4], qv2[4], qv3[4];

  // DMA one 16-ch half-tile: CB = global channel offset (0 or 16)
#define DMA(BUF, PTR, CB) do {                                                \
    const float* sb0 = (PTR) + ibase + (size_t)((CB) + 2 * w) * PLANE;        \
    const float* sb1 = sb0 + PLANE;                                           \
    float* db = smem + (BUF) * 20480 + (2 * w) * 1280;                        \
    _Pragma("unroll")                                                         \
    for (int j = 0; j < 5; ++j) dma16(sb0 + srow[j], db + j * 256);           \
    _Pragma("unroll")                                                         \
    for (int j = 0; j < 5; ++j) dma16(sb1 + srow[j], db + 1280 + j * 256);    \
  } while (0)

#define LQ(QW, G) do {                                                        \
    const float* qg = q + cbase + (size_t)((G) * 8) * PLANE + yx;             \
    _Pragma("unroll")                                                         \
    for (int c = 0; c < 4; ++c)                                               \
      QW[c] = *reinterpret_cast<const float4*>(qg + (size_t)c * PLANE);       \
  } while (0)

  // LDS read: local ch CL (0..15), tile row w+DY (= global y+DY-1)
#define SKV(BUF, CL, DY)                                                      \
  (*reinterpret_cast<const float4*>(                                          \
      smem + (BUF) * 20480 + (CL) * 1280 + (w + (DY)) * 128 + x0))

#define CQK1(BUF, QW, GL) do {                                                \
    _Pragma("unroll")                                                         \
    for (int c = 0; c < 4; ++c) {                                             \
      const float qa[4] = {QW[c].x * SCALE, QW[c].y * SCALE,                  \
                           QW[c].z * SCALE, QW[c].w * SCALE};                 \
      _Pragma("unroll")                                                       \
      for (int dy = 0; dy < 3; ++dy) {                                        \
        float4 kq = SKV(BUF, (GL) * 8 + h2 * 4 + c, dy);                      \
        float n0 = __shfl_up(kq.w, 2);                                        \
        float n5 = __shfl_down(kq.x, 2);                                      \
        const float n[6] = {n0, kq.x, kq.y, kq.z, kq.w, n5};                  \
        _Pragma("unroll")                                                     \
        for (int i = 0; i < 4; ++i)                                           \
          _Pragma("unroll")                                                   \
          for (int j = 0; j < 3; ++j)                                         \
            l[i][dy * 3 + j] += qa[i] * n[i + j];                             \
      }                                                                       \
    }                                                                         \
  } while (0)

#define CPV1(BUF, GL, GO) do {                                                \
    _Pragma("unroll")                                                         \
    for (int c = 0; c < 4; ++c)                                               \
      _Pragma("unroll")                                                       \
      for (int dy = 0; dy < 3; ++dy) {                                        \
        float4 vq = SKV(BUF, (GL) * 8 + h2 * 4 + c, dy);                      \
        float n0 = __shfl_up(vq.w, 2);                                        \
        float n5 = __shfl_down(vq.x, 2);                                      \
        const float n[6] = {n0, vq.x, vq.y, vq.z, vq.w, n5};                  \
        _Pragma("unroll")                                                     \
        for (int i = 0; i < 4; ++i)                                           \
          _Pragma("unroll")                                                   \
          for (int j = 0; j < 3; ++j)                                         \
            acc[i][(GO) * 4 + c] += l[i][dy * 3 + j] * n[i + j];              \
      }                                                                       \
  } while (0)

  const size_t obase = ((size_t)(b * PLANE + y * HW)) * 128 + head * 32 + h2 * 4;
#define ST(P) do {                                                            \
    _Pragma("unroll")                                                         \
    for (int i = 0; i < 4; ++i) {                                             \
      float* op = out + obase + (size_t)(x0 + i) * 128 + (P) * 16;            \
      float4 o;                                                               \
      o.x = fmaxf(acc[i][(P) * 8 + 0], 0.f);                                  \
      o.y = fmaxf(acc[i][(P) * 8 + 1], 0.f);                                  \
      o.z = fmaxf(acc[i][(P) * 8 + 2], 0.f);                                  \
      o.w = fmaxf(acc[i][(P) * 8 + 3], 0.f);                                  \
      *reinterpret_cast<float4*>(op) = o;                                     \
      o.x = fmaxf(acc[i][(P) * 8 + 4], 0.f);                                  \
      o.y = fmaxf(acc[i][(P) * 8 + 5], 0.f);                                  \
      o.z = fmaxf(acc[i][(P) * 8 + 6], 0.f);                                  \
      o.w = fmaxf(acc[i][(P) * 8 + 7], 0.f);                                  \
      *reinterpret_cast<float4*>(op + 8) = o;                                 \
    }                                                                         \
  } while (0)

  // ---- prologue: q g0,g1 | DMA K-lo -> buf0; drain; barrier ----
  LQ(qv0, 0);   FENCE();
  LQ(qv1, 1);   FENCE();
  DMA(0, k, 0); FENCE();
  VMW(0); BAR(); FENCE();

  // ---- P1: DMA K-hi -> buf1 (older) | q g2,g3 (younger) | QK-lo(buf0) ----
  DMA(1, k, 16); FENCE();
  LQ(qv2, 2);    FENCE();
  LQ(qv3, 3);    FENCE();
  CQK1(0, qv0, 0); CQK1(0, qv1, 1); FENCE();
  VMW(8); BAR(); FENCE();          // K-hi (oldest 10) retired; q g2,g3 fly

  // ---- P2: DMA V-lo -> buf0 | QK-hi(buf1) | reduce+softmax ----
  DMA(0, v, 0); FENCE();
  CQK1(1, qv2, 0); CQK1(1, qv3, 1); FENCE();

#pragma unroll
  for (int i = 0; i < 4; ++i)
#pragma unroll
    for (int j = 0; j < 9; ++j) l[i][j] += __shfl_xor(l[i][j], 1);
#pragma unroll
  for (int i = 0; i < 4; ++i) {
    const int xp = x0 + i;
    float mk[9];
#pragma unroll
    for (int dy = 0; dy < 3; ++dy)
#pragma unroll
      for (int dx = 0; dx < 3; ++dx) {
        bool ok = ((unsigned)(y + dy - 1) < (unsigned)HW) &&
                  ((unsigned)(xp + dx - 1) < (unsigned)HW);
        mk[dy * 3 + dx] = ok ? 1.f : 0.f;
      }
    float m = -1e30f;
#pragma unroll
    for (int j = 0; j < 9; ++j) {
      float t = l[i][j] * mk[j];
      l[i][j] = t;
      m = fmaxf(m, t);
    }
    float sum = 0.f;
#pragma unroll
    for (int j = 0; j < 9; ++j) {
      float e = __expf(l[i][j] - m);
      l[i][j] = e;
      sum += e;
    }
    float inv = 1.f / sum;
#pragma unroll
    for (int j = 0; j < 9; ++j) l[i][j] *= inv * mk[j];
  }
  FENCE();
  VMW(0); BAR(); FENCE();          // V-lo landed

  // ---- P3: DMA V-hi -> buf1 | PV-lo(buf0) | stores ch0-15 ----
  DMA(1, v, 16); FENCE();
  CPV1(0, 0, 0); CPV1(0, 1, 1); FENCE();
  ST(0); FENCE();
  VMW(8); BAR(); FENCE();          // V-hi (oldest 10) retired; stores fly

  // ---- P4: PV-hi(buf1) | stores ch16-31 ----
  CPV1(1, 0, 2); CPV1(1, 1, 3); FENCE();
  ST(1);

#undef DMA
#undef LQ
#undef SKV
#undef CQK1
#undef CPV1
#undef ST
}

extern "C" void kernel_launch(void* const* d_in, const int* in_sizes, int n_in,
                              void* d_out, int out_size, void* d_ws, size_t ws_size,
                              hipStream_t stream) {
  const float* q = (const float*)d_in[0];
  const float* k = (const float*)d_in[1];
  const float* v = (const float*)d_in[2];
  float* out = (float*)d_out;
  // grid: 256 blocks (XCD-swizzled decode in-kernel), 512 threads (8 waves)
  natt3x3_kernel<<<256, 512, 0, stream>>>(q, k, v, out);
}

// Round 18
// 28.069 us; speedup vs baseline: 1.1341x; 1.0989x over previous
//
#include <hip/hip_runtime.h>

#define HW 128
#define PLANE (HW * HW)              // 16384
#define SCALE 0.17677669529663687f   // 32^-0.5
#define FENCE() asm volatile("" ::: "memory")

// FINAL (R15 reproduction): R12 structure + XCD-aware blockIdx swizzle.
// Thread = 4px x 16ch; lane = (strip<<1)|h2; wave = one row; block = 8 waves
// = 8-row tile (halo 1.25x). Channels per thread: g*8 + h2*4 + {0..3} ->
// pair-contiguous 32B stores, fused single store phase (64B-sector-complete,
// normal stores so L2 merges). Fence-pinned 3-buffer register pipeline keeps
// 2-3 16-load groups in flight; PV prefetch hides under softmax. XCD swizzle:
// xcd = bid&7 gets images {2x,2x+1} only -> k/v reuse + halo confined to one
// L2 (R15: +6.5%). Grid = 256 blocks x 512 thr = 1 block/CU, 8 waves/CU.
// LDS-staging falsified 3x (R7/R16/R17): barriers cost more than the L2
// re-reads they save on this L3-resident op.
__global__ __launch_bounds__(512, 2) void natt3x3_kernel(
    const float* __restrict__ q,
    const float* __restrict__ k,
    const float* __restrict__ v,
    float* __restrict__ out) {
  const int tid  = threadIdx.x;
  const int lane = tid & 63;
  const int w    = tid >> 6;            // wave index in block = row in tile (0..7)
  const int h2   = lane & 1;            // channel sub-quad selector
  const int s    = lane >> 1;           // strip 0..31
  const int x0   = s << 2;              // first pixel x of strip
  const int bid  = blockIdx.x;
  const int img   = ((bid & 7) << 1) | ((bid >> 3) & 1);   // XCD swizzle
  const int ytile = bid >> 4;                              // 0..15
  const int head  = img & 3;
  const int b     = img >> 2;
  const int y     = (ytile << 3) | w;

  const size_t cbase = (size_t)(b * 128 + head * 32 + h2 * 4) * PLANE;
  const int yx = y * HW + x0;

  int yrow[3];
#pragma unroll
  for (int dy = 0; dy < 3; ++dy) {
    int yy = y + dy - 1; yy = yy < 0 ? 0 : (yy > HW - 1 ? HW - 1 : yy);
    yrow[dy] = yy * HW;
  }

  float l[4][9];
#pragma unroll
  for (int i = 0; i < 4; ++i)
#pragma unroll
    for (int j = 0; j < 9; ++j) l[i][j] = 0.f;

  float acc[4][16];     // all 16 channels per pixel, stored once at the end
#pragma unroll
  for (int i = 0; i < 4; ++i)
#pragma unroll
    for (int c = 0; c < 16; ++c) acc[i][c] = 0.f;

  float4 qv4[3][4];      // q quads per buffer
  float4 rv[3][3][4];    // k/v rows [buf][dy][c]

#define LQK(B, G) do {                                                       \
    const size_t cb = cbase + (size_t)((G) * 8) * PLANE;                     \
    const float* qg = q + cb + yx;                                           \
    const float* kg = k + cb;                                                \
    _Pragma("unroll")                                                        \
    for (int c = 0; c < 4; ++c)                                              \
      qv4[B][c] = *reinterpret_cast<const float4*>(qg + (size_t)c * PLANE);  \
    _Pragma("unroll")                                                        \
    for (int c = 0; c < 4; ++c)                                              \
      _Pragma("unroll")                                                      \
      for (int dy = 0; dy < 3; ++dy)                                         \
        rv[B][dy][c] = *reinterpret_cast<const float4*>(                     \
            kg + (size_t)c * PLANE + yrow[dy] + x0);                         \
  } while (0)

#define LPV(B, G) do {                                                       \
    const float* vg = v + cbase + (size_t)((G) * 8) * PLANE;                 \
    _Pragma("unroll")                                                        \
    for (int c = 0; c < 4; ++c)                                              \
      _Pragma("unroll")                                                      \
      for (int dy = 0; dy < 3; ++dy)                                         \
        rv[B][dy][c] = *reinterpret_cast<const float4*>(                     \
            vg + (size_t)c * PLANE + yrow[dy] + x0);                         \
  } while (0)

#define CQK(B) do {                                                          \
    _Pragma("unroll")                                                        \
    for (int c = 0; c < 4; ++c) {                                            \
      const float qa[4] = {qv4[B][c].x * SCALE, qv4[B][c].y * SCALE,         \
                           qv4[B][c].z * SCALE, qv4[B][c].w * SCALE};        \
      _Pragma("unroll")                                                      \
      for (int dy = 0; dy < 3; ++dy) {                                       \
        float4 kq = rv[B][dy][c];                                            \
        float n0 = __shfl_up(kq.w, 2);                                       \
        float n5 = __shfl_down(kq.x, 2);                                     \
        const float n[6] = {n0, kq.x, kq.y, kq.z, kq.w, n5};                 \
        _Pragma("unroll")                                                    \
        for (int i = 0; i < 4; ++i)                                          \
          _Pragma("unroll")                                                  \
          for (int j = 0; j < 3; ++j)                                        \
            l[i][dy * 3 + j] += qa[i] * n[i + j];                            \
      }                                                                      \
    }                                                                        \
  } while (0)

#define CPV(B, G) do {                                                       \
    _Pragma("unroll")                                                        \
    for (int c = 0; c < 4; ++c)                                              \
      _Pragma("unroll")                                                      \
      for (int dy = 0; dy < 3; ++dy) {                                       \
        float4 vq = rv[B][dy][c];                                            \
        float n0 = __shfl_up(vq.w, 2);                                       \
        float n5 = __shfl_down(vq.x, 2);                                     \
        const float n[6] = {n0, vq.x, vq.y, vq.z, vq.w, n5};                 \
        _Pragma("unroll")                                                    \
        for (int i = 0; i < 4; ++i)                                          \
          _Pragma("unroll")                                                  \
          for (int j = 0; j < 3; ++j)                                        \
            acc[i][(G) * 4 + c] += l[i][dy * 3 + j] * n[i + j];              \
      }                                                                      \
  } while (0)

  // ---- QK: fence-pinned schedule, 2-3 load-groups in flight ----
  LQK(0, 0); FENCE();
  LQK(1, 1); FENCE();
  LQK(2, 2); FENCE();
  CQK(0);    FENCE();
  LQK(0, 3); FENCE();
  CQK(1);    FENCE();
  LPV(1, 0); FENCE();
  CQK(2);    FENCE();
  LPV(2, 1); FENCE();
  CQK(0);    FENCE();   // group 3
  LPV(0, 2); FENCE();

  // ---- lane-pair reduce: my 16 channels + partner's 16 = full 32 ----
#pragma unroll
  for (int i = 0; i < 4; ++i)
#pragma unroll
    for (int j = 0; j < 9; ++j) l[i][j] += __shfl_xor(l[i][j], 1);

  // ---- mask + softmax per pixel (3 PV load-groups in flight under this) ----
#pragma unroll
  for (int i = 0; i < 4; ++i) {
    const int xp = x0 + i;
    float mk[9];
#pragma unroll
    for (int dy = 0; dy < 3; ++dy)
#pragma unroll
      for (int dx = 0; dx < 3; ++dx) {
        bool ok = ((unsigned)(y + dy - 1) < (unsigned)HW) &&
                  ((unsigned)(xp + dx - 1) < (unsigned)HW);
        mk[dy * 3 + dx] = ok ? 1.f : 0.f;
      }
    float m = -1e30f;
#pragma unroll
    for (int j = 0; j < 9; ++j) {
      float t = l[i][j] * mk[j];
      l[i][j] = t;
      m = fmaxf(m, t);
    }
    float sum = 0.f;
#pragma unroll
    for (int j = 0; j < 9; ++j) {
      float e = __expf(l[i][j] - m);
      l[i][j] = e;
      sum += e;
    }
    float inv = 1.f / sum;
#pragma unroll
    for (int j = 0; j < 9; ++j) l[i][j] *= inv * mk[j];
  }
  FENCE();

  // ---- PV: accumulate only (no stores yet) ----
  CPV(1, 0); FENCE();
  LPV(1, 3); FENCE();
  CPV(2, 1); FENCE();
  CPV(0, 2); FENCE();
  CPV(1, 3);

  // ---- single store phase: 16 normal float4, back-to-back ----
  const size_t obase = ((size_t)(b * PLANE + y * HW)) * 128 + head * 32 + h2 * 4;
#pragma unroll
  for (int i = 0; i < 4; ++i) {
    float* op = out + obase + (size_t)(x0 + i) * 128;
#pragma unroll
    for (int g = 0; g < 4; ++g) {
      float4 o;
      o.x = fmaxf(acc[i][g * 4 + 0], 0.f);
      o.y = fmaxf(acc[i][g * 4 + 1], 0.f);
      o.z = fmaxf(acc[i][g * 4 + 2], 0.f);
      o.w = fmaxf(acc[i][g * 4 + 3], 0.f);
      *reinterpret_cast<float4*>(op + g * 8) = o;
    }
  }

#undef LQK
#undef LPV
#undef CQK
#undef CPV
}

extern "C" void kernel_launch(void* const* d_in, const int* in_sizes, int n_in,
                              void* d_out, int out_size, void* d_ws, size_t ws_size,
                              hipStream_t stream) {
  const float* q = (const float*)d_in[0];
  const float* k = (const float*)d_in[1];
  const float* v = (const float*)d_in[2];
  float* out = (float*)d_out;
  // grid: 256 blocks (XCD-swizzled decode in-kernel), 512 threads (8 waves)
  natt3x3_kernel<<<256, 512, 0, stream>>>(q, k, v, out);
}